// Round 4
// baseline (6168.473 us; speedup 1.0000x reference)
//
#include <hip/hip_runtime.h>
#include <hip/hip_bf16.h>
#include <math.h>

#define BB 64
#define HW 196
#define FEAT 2048
#define EMB 512
#define HID 1024
#define ATT 512
#define VOCAB 10000
#define TT 20
#define STEPS 19

#define G_BLOCKS 256
#define G_THREADS 1024

__device__ __forceinline__ float sigmoidf_(float x) { return 1.0f / (1.0f + expf(-x)); }

using bfrag = __attribute__((ext_vector_type(8))) short;   // 8 bf16 = 4 VGPR
using f32x4 = __attribute__((ext_vector_type(4))) float;

__device__ __forceinline__ ushort f2bf_rne(float f) {
    unsigned u = __float_as_uint(f);
    unsigned r = (u + 0x7FFFu + ((u >> 16) & 1u)) >> 16;
    return (ushort)r;
}
__device__ __forceinline__ float bf2f(ushort h) {
    return __uint_as_float(((unsigned)h) << 16);
}

// ---------------------------------------------------------------------------
// fp32 -> split bf16 planes: x = hi + lo.  n % 1024 == 0.
// ---------------------------------------------------------------------------
__global__ __launch_bounds__(256) void k_split(const float* __restrict__ x,
                                               ushort* __restrict__ hi,
                                               ushort* __restrict__ lo, int n)
{
    int i4 = (blockIdx.x * 256 + threadIdx.x) * 4;
    if (i4 >= n) return;
    float4 v = *(const float4*)(x + i4);
    float av[4] = {v.x, v.y, v.z, v.w};
    #pragma unroll
    for (int j = 0; j < 4; ++j) {
        ushort h = f2bf_rne(av[j]);
        hi[i4 + j] = h;
        lo[i4 + j] = f2bf_rne(av[j] - bf2f(h));
    }
}

// ---------------------------------------------------------------------------
// MFMA split-bf16 NT GEMM (unchanged from R3): C = A.B^T + bias, 3-term.
// ---------------------------------------------------------------------------
__global__ __launch_bounds__(256) void mfma_nt(
    const float* __restrict__ A,
    const ushort* __restrict__ Bhi, const ushort* __restrict__ Blo,
    const float* __restrict__ bias, float* __restrict__ C,
    int Mvalid, int N, int K, int ldc)
{
    __shared__ __align__(16) ushort sAh[4][64][8];
    __shared__ __align__(16) ushort sAl[4][64][8];
    __shared__ __align__(16) ushort sBh[4][256][8];
    __shared__ __align__(16) ushort sBl[4][256][8];

    const int tid = threadIdx.x;
    const int m0 = blockIdx.y * 64;
    const int n0 = blockIdx.x * 256;

    const int ag = tid >> 6, ar = tid & 63;
    const float* aptr = A + (size_t)(m0 + ar) * K + ag * 8;
    const int nr = min(n0 + tid, N - 1);
    const ushort* bhp = Bhi + (size_t)nr * K;
    const ushort* blp = Blo + (size_t)nr * K;

    const int lane = tid & 63;
    const int w = tid >> 6;
    const int g = lane >> 4, l15 = lane & 15;

    f32x4 acc[4][4] = {};

    for (int k0 = 0; k0 < K; k0 += 32) {
        __syncthreads();
        {
            float av[8];
            *(float4*)(av)     = *(const float4*)(aptr + k0);
            *(float4*)(av + 4) = *(const float4*)(aptr + k0 + 4);
            bfrag vh, vl;
            #pragma unroll
            for (int j = 0; j < 8; ++j) {
                ushort h = f2bf_rne(av[j]);
                vh[j] = (short)h;
                vl[j] = (short)f2bf_rne(av[j] - bf2f(h));
            }
            *(bfrag*)&sAh[ag][ar][0] = vh;
            *(bfrag*)&sAl[ag][ar][0] = vl;
        }
        #pragma unroll
        for (int q = 0; q < 4; ++q) {
            *(bfrag*)&sBh[q][tid][0] = *(const bfrag*)(bhp + k0 + q * 8);
            *(bfrag*)&sBl[q][tid][0] = *(const bfrag*)(blp + k0 + q * 8);
        }
        __syncthreads();

        bfrag ah[4], al[4], bh[4], bl[4];
        #pragma unroll
        for (int s = 0; s < 4; ++s) {
            ah[s] = *(const bfrag*)&sAh[g][s * 16 + l15][0];
            al[s] = *(const bfrag*)&sAl[g][s * 16 + l15][0];
        }
        #pragma unroll
        for (int u = 0; u < 4; ++u) {
            bh[u] = *(const bfrag*)&sBh[g][w * 64 + u * 16 + l15][0];
            bl[u] = *(const bfrag*)&sBl[g][w * 64 + u * 16 + l15][0];
        }
        #pragma unroll
        for (int s = 0; s < 4; ++s)
            #pragma unroll
            for (int u = 0; u < 4; ++u) {
                acc[s][u] = __builtin_amdgcn_mfma_f32_16x16x32_bf16(ah[s], bh[u], acc[s][u], 0, 0, 0);
                acc[s][u] = __builtin_amdgcn_mfma_f32_16x16x32_bf16(ah[s], bl[u], acc[s][u], 0, 0, 0);
                acc[s][u] = __builtin_amdgcn_mfma_f32_16x16x32_bf16(al[s], bh[u], acc[s][u], 0, 0, 0);
            }
    }

    #pragma unroll
    for (int s = 0; s < 4; ++s)
        #pragma unroll
        for (int u = 0; u < 4; ++u) {
            int col = n0 + w * 64 + u * 16 + l15;
            if (col < N) {
                float bv = bias[col];
                #pragma unroll
                for (int r = 0; r < 4; ++r) {
                    int row = m0 + s * 16 + g * 4 + r;
                    if (row < Mvalid)
                        C[(size_t)row * ldc + col] = acc[s][u][r] + bv;
                }
            }
        }
}

// ---------------------------------------------------------------------------
__global__ __launch_bounds__(256) void k_fmean(const float* __restrict__ f,
                                               float* __restrict__ fmean)
{
    int b = blockIdx.x, tid = threadIdx.x;
    for (int e = tid; e < EMB; e += 256) {
        const float* fb = f + (size_t)b * HW * EMB + e;
        float s = 0.f;
        for (int h = 0; h < HW; ++h) s += fb[(size_t)h * EMB];
        fmean[b * EMB + e] = s * (1.0f / HW);
    }
}

__global__ __launch_bounds__(256) void k_init(
    const float* __restrict__ fmean,
    const float* __restrict__ W_hi, const float* __restrict__ b_hi,
    const float* __restrict__ W_ci, const float* __restrict__ b_ci,
    float* __restrict__ hx, float* __restrict__ cx)
{
    int b = blockIdx.x, tid = threadIdx.x;
    __shared__ float fm[EMB];
    for (int i = tid; i < EMB; i += 256) fm[i] = fmean[b * EMB + i];
    __syncthreads();
    for (int u = tid; u < HID; u += 256) {
        const float4* w1 = (const float4*)(W_hi + (size_t)u * EMB);
        const float4* w2 = (const float4*)(W_ci + (size_t)u * EMB);
        float a1 = b_hi[u], a2 = b_ci[u];
        for (int k = 0; k < EMB / 4; ++k) {
            float4 y1 = w1[k], y2 = w2[k];
            float x0 = fm[4*k], x1 = fm[4*k+1], x2 = fm[4*k+2], x3 = fm[4*k+3];
            a1 += x0*y1.x + x1*y1.y + x2*y1.z + x3*y1.w;
            a2 += x0*y2.x + x1*y2.y + x2*y2.z + x3*y2.w;
        }
        hx[b * HID + u] = a1;
        cx[b * HID + u] = a2;
    }
}

__global__ __launch_bounds__(128) void k_embed(const int* __restrict__ cap,
                                               const float* __restrict__ E,
                                               float* __restrict__ xs)
{
    int blk = blockIdx.x;
    int t = blk / BB, b = blk % BB;
    int c = cap[b * TT + t];
    const float4* src = (const float4*)(E + (size_t)c * EMB);
    float4* dst = (float4*)(xs + ((size_t)t * BB + b) * EMB);
    dst[threadIdx.x] = src[threadIdx.x];
}

__global__ void k_bar_init(int* bar) { bar[0] = 0; bar[1] = 0; }

// ---------------------------------------------------------------------------
// Persistent step-loop kernel. grid = 256 blocks x 1024 threads, all
// co-resident by construction (16 waves, 64KB LDS, VGPR<=128 -> every CU
// hosts >=1 block; grid == #CUs so no block can be stranded).
// Hand-rolled sense-reversal grid barrier, agent-scope atomics (cross-XCD).
// ---------------------------------------------------------------------------
__device__ __forceinline__ void grid_barrier(int* cnt, int* gen) {
    __syncthreads();
    if (threadIdx.x == 0) {
        __threadfence();   // agent-scope release of this block's writes
        int g = __hip_atomic_load(gen, __ATOMIC_RELAXED, __HIP_MEMORY_SCOPE_AGENT);
        if (__hip_atomic_fetch_add(cnt, 1, __ATOMIC_ACQ_REL, __HIP_MEMORY_SCOPE_AGENT)
            == G_BLOCKS - 1) {
            __hip_atomic_store(cnt, 0, __ATOMIC_RELEASE, __HIP_MEMORY_SCOPE_AGENT);
            __hip_atomic_fetch_add(gen, 1, __ATOMIC_RELEASE, __HIP_MEMORY_SCOPE_AGENT);
        } else {
            while (__hip_atomic_load(gen, __ATOMIC_ACQUIRE, __HIP_MEMORY_SCOPE_AGENT) == g)
                __builtin_amdgcn_s_sleep(2);
        }
    }
    __syncthreads();
}

__global__ __launch_bounds__(G_THREADS, 4) void k_steps(
    const float* __restrict__ xs, const float* __restrict__ f,
    const float* __restrict__ fa,
    const float* __restrict__ W2, const float* __restrict__ b2,
    const float* __restrict__ V, const float* __restrict__ bV,
    const float* __restrict__ W_ih, const float* __restrict__ b_ih,
    const float* __restrict__ W_hh, const float* __restrict__ b_hh,
    float* __restrict__ hx, float* __restrict__ cx,
    float* __restrict__ ha, float* __restrict__ logits,
    float* __restrict__ ctxb, float* __restrict__ gates_T,
    float* __restrict__ hx_all, int* __restrict__ bar)
{
    __shared__ __align__(16) float smem[16384];   // 64 KB, aliased per phase
    const int tid = threadIdx.x;
    const int blk = blockIdx.x;
    const int lane = tid & 63;
    const int wid = tid >> 6;          // 0..15
    const int gw = blk * 16 + wid;     // global wave 0..4095
    int* cnt = bar; int* gen = bar + 1;

    for (int t = 0; t < STEPS; ++t) {
        const float* xs_t = xs + (size_t)t * BB * EMB;

        // ---- Phase A: ha[b][a] = hx[b].W2[a] + b2[a]  (8 outputs/wave) ----
        #pragma unroll 2
        for (int i = 0; i < 8; ++i) {
            int o = gw * 8 + i;                 // 0..32767
            int b = o >> 9, a = o & 511;
            const float4* wr = (const float4*)(W2 + (size_t)a * HID) + lane * 4;
            const float4* xr = (const float4*)(hx + (size_t)b * HID) + lane * 4;
            float s = 0.f;
            #pragma unroll
            for (int q = 0; q < 4; ++q) {
                float4 w = wr[q], x = xr[q];
                s += w.x*x.x + w.y*x.y + w.z*x.z + w.w*x.w;
            }
            #pragma unroll
            for (int off = 32; off > 0; off >>= 1) s += __shfl_down(s, off);
            if (lane == 0) ha[o] = s + b2[a];
        }
        grid_barrier(cnt, gen);

        // ---- Phase B: logits[b][h] (<=4 outputs/wave) ----
        for (int o = gw; o < BB * HW; o += 4096) {
            int b = o / HW, h = o - b * HW;
            const float4* far = (const float4*)(fa + ((size_t)b * HW + h) * ATT) + lane * 2;
            const float4* har = (const float4*)(ha + (size_t)b * ATT) + lane * 2;
            const float4* vr  = (const float4*)V + lane * 2;
            float s = 0.f;
            #pragma unroll
            for (int q = 0; q < 2; ++q) {
                float4 fv = far[q], hv = har[q], vv = vr[q];
                s += tanhf(fv.x + hv.x) * vv.x + tanhf(fv.y + hv.y) * vv.y
                   + tanhf(fv.z + hv.z) * vv.z + tanhf(fv.w + hv.w) * vv.w;
            }
            #pragma unroll
            for (int off = 32; off > 0; off >>= 1) s += __shfl_down(s, off);
            if (lane == 0) logits[o] = s + bV[0];
        }
        grid_barrier(cnt, gen);

        // ---- Phase C: softmax over HW + ctx (4 blocks per b) ----
        {
            int b = blk >> 2, eq = blk & 3;
            float* w_s  = smem;            // 196
            float* red  = smem + 256;      // 256
            float* part = smem + 512;      // 8*128
            float v = (tid < HW) ? logits[b * HW + tid] : -INFINITY;
            if (tid < 256) red[tid] = v;
            __syncthreads();
            for (int s2 = 128; s2 > 0; s2 >>= 1) {
                if (tid < s2) red[tid] = fmaxf(red[tid], red[tid + s2]);
                __syncthreads();
            }
            float mx = red[0];
            __syncthreads();
            float e = (tid < HW) ? expf(v - mx) : 0.f;
            if (tid < 256) red[tid] = e;
            __syncthreads();
            for (int s2 = 128; s2 > 0; s2 >>= 1) {
                if (tid < s2) red[tid] += red[tid + s2];
                __syncthreads();
            }
            float inv = 1.0f / red[0];
            if (tid < HW) w_s[tid] = e * inv;
            __syncthreads();
            int el = tid & 127, grp = tid >> 7;
            int e0 = eq * 128 + el;
            const float* fb = f + (size_t)b * HW * EMB + e0;
            float s = 0.f;
            for (int h = grp; h < HW; h += 8)
                s = fmaf(w_s[h], fb[(size_t)h * EMB], s);
            part[grp * 128 + el] = s;
            __syncthreads();
            if (grp == 0) {
                float acc = s;
                #pragma unroll
                for (int g2 = 1; g2 < 8; ++g2) acc += part[g2 * 128 + el];
                ctxb[b * EMB + e0] = acc;
            }
            __syncthreads();
        }
        grid_barrier(cnt, gen);

        // ---- Phase D: gates_T[n][b] = act[b].Wcat[n]  (1 col/wave) ----
        {
            float4* lds4 = (float4*)smem;   // [64 rows][64 float4], swizzled
            const int n = gw;               // 0..4095
            float acc = 0.f;
            for (int c = 0; c < 8; ++c) {
                const float* src; int ald, koff; const float* wrow;
                if (c < 2)      { src = xs_t; ald = 512;  koff = c * 256;
                                  wrow = W_ih + (size_t)n * 1024 + c * 256; }
                else if (c < 4) { src = ctxb; ald = 512;  koff = (c - 2) * 256;
                                  wrow = W_ih + (size_t)n * 1024 + 512 + (c - 2) * 256; }
                else            { src = hx;  ald = 1024; koff = (c - 4) * 256;
                                  wrow = W_hh + (size_t)n * 1024 + (c - 4) * 256; }
                __syncthreads();
                #pragma unroll
                for (int p = 0; p < 4; ++p) {
                    int idx = tid + p * 1024;      // 0..4095
                    int r = idx >> 6, j = idx & 63;
                    float4 v = *(const float4*)(src + (size_t)r * ald + koff + j * 4);
                    lds4[(r << 6) | (j ^ (r & 7))] = v;
                }
                __syncthreads();
                const float4* wr4 = (const float4*)wrow;
                #pragma unroll 8
                for (int j = 0; j < 64; ++j) {
                    float4 a = lds4[(lane << 6) | (j ^ (lane & 7))];
                    float4 w = wr4[j];
                    acc += a.x*w.x + a.y*w.y + a.z*w.z + a.w*w.w;
                }
            }
            gates_T[(size_t)n * 64 + lane] = acc;
        }
        grid_barrier(cnt, gen);

        // ---- Phase E: LSTM pointwise ----
        {
            int g = blk * 1024 + tid;
            if (g < BB * HID) {
                int u = g & 1023, b = g >> 10;
                float gi = gates_T[(size_t)u * 64 + b]          + b_ih[u]        + b_hh[u];
                float gf = gates_T[(size_t)(1024 + u) * 64 + b] + b_ih[1024 + u] + b_hh[1024 + u];
                float gg = gates_T[(size_t)(2048 + u) * 64 + b] + b_ih[2048 + u] + b_hh[2048 + u];
                float go = gates_T[(size_t)(3072 + u) * 64 + b] + b_ih[3072 + u] + b_hh[3072 + u];
                float c = sigmoidf_(gf) * cx[g] + sigmoidf_(gi) * tanhf(gg);
                float h = sigmoidf_(go) * tanhf(c);
                cx[g] = c; hx[g] = h;
                hx_all[(size_t)t * BB * HID + g] = h;
            }
        }
        grid_barrier(cnt, gen);
    }
}

// ---------------------------------------------------------------------------
extern "C" void kernel_launch(void* const* d_in, const int* in_sizes, int n_in,
                              void* d_out, int out_size, void* d_ws, size_t ws_size,
                              hipStream_t stream) {
    const float* features = (const float*)d_in[0];
    const int*   captions = (const int*)d_in[1];
    const float* E      = (const float*)d_in[3];
    const float* W_feat = (const float*)d_in[4];
    const float* b_feat = (const float*)d_in[5];
    const float* W1     = (const float*)d_in[6];
    const float* b1     = (const float*)d_in[7];
    const float* W2     = (const float*)d_in[8];
    const float* b2     = (const float*)d_in[9];
    const float* V      = (const float*)d_in[10];
    const float* bV     = (const float*)d_in[11];
    const float* W_hi   = (const float*)d_in[12];
    const float* b_hi   = (const float*)d_in[13];
    const float* W_ci   = (const float*)d_in[14];
    const float* b_ci   = (const float*)d_in[15];
    const float* W_ih   = (const float*)d_in[16];
    const float* b_ih   = (const float*)d_in[17];
    const float* W_hh   = (const float*)d_in[18];
    const float* b_hh   = (const float*)d_in[19];
    const float* W_out  = (const float*)d_in[20];
    const float* b_out  = (const float*)d_in[21];
    float* out = (float*)d_out;

    // ---- workspace layout (floats, then ushort planes) ----
    float* ws = (float*)d_ws;
    float* f_buf   = ws;                         // 6,422,528
    float* fa_buf  = f_buf + 6422528;            // 6,422,528
    float* xs      = fa_buf + 6422528;           // 622,592
    float* fmean   = xs + 622592;                // 32,768
    float* hx      = fmean + 32768;              // 65,536
    float* cx      = hx + 65536;                 // 65,536
    float* ctxb    = cx + 65536;                 // 32,768
    float* ha      = ctxb + 32768;               // 32,768
    float* logits  = ha + 32768;                 // 12,544
    float* gates_T = logits + 12544;             // 262,144
    float* hx_all  = gates_T + 262144;           // 1,310,720
    int*   bar     = (int*)(hx_all + 1310720);   // 16 floats reserved
    ushort* wfeat_hi = (ushort*)(hx_all + 1310720 + 16);
    ushort* wfeat_lo = wfeat_hi + 1048576;
    ushort* w1_hi    = wfeat_lo + 1048576;
    ushort* w1_lo    = w1_hi + 262144;
    // W_out planes reuse f_buf/fa_buf region after the step loop
    ushort* wout_hi = (ushort*)f_buf;
    ushort* wout_lo = wout_hi + 10240000;

    // ---- precompute ----
    k_bar_init<<<1, 1, 0, stream>>>(bar);
    k_split<<<1048576 / 4 / 256, 256, 0, stream>>>(W_feat, wfeat_hi, wfeat_lo, 1048576);
    k_split<<<262144 / 4 / 256, 256, 0, stream>>>(W1, w1_hi, w1_lo, 262144);
    mfma_nt<<<dim3(2, 196), 256, 0, stream>>>(
        features, wfeat_hi, wfeat_lo, b_feat, f_buf, 12544, 512, 2048, 512);
    mfma_nt<<<dim3(2, 196), 256, 0, stream>>>(
        f_buf, w1_hi, w1_lo, b1, fa_buf, 12544, 512, 512, 512);
    k_fmean<<<BB, 256, 0, stream>>>(f_buf, fmean);
    k_init<<<BB, 256, 0, stream>>>(fmean, W_hi, b_hi, W_ci, b_ci, hx, cx);
    k_embed<<<STEPS * BB, 128, 0, stream>>>(captions, E, xs);

    // ---- all 19 recurrent steps in one persistent kernel ----
    k_steps<<<G_BLOCKS, G_THREADS, 0, stream>>>(
        xs, f_buf, fa_buf, W2, b2, V, bV, W_ih, b_ih, W_hh, b_hh,
        hx, cx, ha, logits, ctxb, gates_T, hx_all, bar);

    // ---- vocab projection over all steps at once: [1216,10000], K=1024 ----
    k_split<<<10240000 / 4 / 256, 256, 0, stream>>>(W_out, wout_hi, wout_lo, 10240000);
    mfma_nt<<<dim3(40, 20), 256, 0, stream>>>(
        hx_all, wout_hi, wout_lo, b_out, out, STEPS * BB, VOCAB, HID, VOCAB);
}